// Round 1
// baseline (198.308 us; speedup 1.0000x reference)
//
#include <hip/hip_runtime.h>
#include <cmath>

// MenuLoss: scalar loss over y_pred/y of shape (512, 7, 16, 64, 2) fp32.
// Pred-side Chebyshev collapses to a 223-entry table (ids are rounded to
// integers 0..222 before eval); true side needs full deg-446 Clenshaw-style
// recurrence per point -> ~3.27e9 FMA, compute-bound (~41.6 us VALU floor).

constexpr int NCOEF = 447;
constexpr int NTAB  = 223;
constexpr int THREADS = 256;
constexpr int F4_PER_BATCH = 3584;   // 7*16*64*2 floats / 4 per float4
constexpr int NCHUNK = 7;            // 14 float4/thread, 2 per chunk (4 elems)

__global__ __launch_bounds__(THREADS)
void menu_loss_kernel(const float4* __restrict__ y_pred4,
                      const float4* __restrict__ y4,
                      const float* __restrict__ coeffs,
                      float* __restrict__ out)
{
  __shared__ float stab[NTAB];
  __shared__ float sred[12];

  const int tid = threadIdx.x;
  const int b = blockIdx.x;

  // ---- per-block pred-calorie table: cheb(mask(k)) for k = 0..222 ----
  // mask(k) = k * sigmoid(50*(222.5-k)); for integer k<=222 this is k in fp32,
  // but compute it exactly as the reference does.
  if (tid < NTAB) {
    float k = (float)tid;
    float m = k / (1.0f + __expf(50.0f * (k - 222.5f)));
    float xn = m / 111.0f - 1.0f;        // exact div to match reference
    float x2 = xn + xn;
    float Tm = 1.0f, Tc = xn;
    float acc = fmaf(coeffs[1], xn, coeffs[0]);
    for (int i = 2; i < NCOEF; ++i) {    // uniform index -> s_load (scalar pipe)
      float Tn = fmaf(x2, Tc, -Tm);
      acc = fmaf(coeffs[i], Tn, acc);
      Tm = Tc; Tc = Tn;
    }
    stab[tid] = acc;
  }
  __syncthreads();

  const float4* yp = y_pred4 + (size_t)b * F4_PER_BATCH;
  const float4* yt = y4      + (size_t)b * F4_PER_BATCH;

  float pen = 0.0f, ct = 0.0f, cp = 0.0f;

  // software prefetch: load chunk 0 now, chunk k+1 during chunk k's compute
  float4 p0 = yp[tid], p1 = yp[tid + THREADS];
  float4 t0 = yt[tid], t1 = yt[tid + THREADS];

  for (int k = 0; k < NCHUNK; ++k) {
    float4 np0 = p0, np1 = p1, nt0 = t0, nt1 = t1;
    if (k + 1 < NCHUNK) {
      int off = (k + 1) * 2 * THREADS + tid;
      np0 = yp[off]; np1 = yp[off + THREADS];
      nt0 = yt[off]; nt1 = yt[off + THREADS];
    }

    // each float4 = two (id, amount) pairs
    float pid[4] = {p0.x, p0.z, p1.x, p1.z};
    float pam[4] = {p0.y, p0.w, p1.y, p1.w};
    float tix[4] = {t0.x, t0.z, t1.x, t1.z};
    float tam[4] = {t0.y, t0.w, t1.y, t1.w};

    #pragma unroll
    for (int u = 0; u < 4; ++u) {
      // zeros/nonzeros penalty + id range penalty
      float izm = 1.0f - tanhf(4.0f * pid[u]);
      float anm = tanhf(4.0f * pam[u]);
      pen += izm * anm + (1.0f - izm) * (1.0f - anm);
      pen += fmaxf(pid[u] - 222.0f, 0.0f);
      // pred calories via table (round-half-even matches jnp.round)
      int idx = (int)rintf(pid[u]);
      idx = idx < 0 ? 0 : (idx > NTAB - 1 ? NTAB - 1 : idx);
      cp = fmaf(stab[idx], pam[u], cp);
    }

    // true-side Chebyshev, 4-way ILP to hide FMA latency
    float x2[4], Tm[4], Tc[4], acc[4];
    #pragma unroll
    for (int u = 0; u < 4; ++u) {
      float xn = tix[u] / 111.0f - 1.0f;   // exact div to match reference
      x2[u] = xn + xn;
      Tm[u] = 1.0f;
      Tc[u] = xn;
      acc[u] = fmaf(coeffs[1], xn, coeffs[0]);
    }
    #pragma unroll 4
    for (int i = 2; i < NCOEF; ++i) {
      float c = coeffs[i];                 // uniform -> scalar load, no LDS traffic
      #pragma unroll
      for (int u = 0; u < 4; ++u) {
        float Tn = fmaf(x2[u], Tc[u], -Tm[u]);
        acc[u] = fmaf(c, Tn, acc[u]);
        Tm[u] = Tc[u]; Tc[u] = Tn;
      }
    }
    #pragma unroll
    for (int u = 0; u < 4; ++u) ct = fmaf(acc[u], tam[u], ct);

    p0 = np0; p1 = np1; t0 = nt0; t1 = nt1;
  }

  // ---- block reduction: pen (global sum), ct/cp (per-batch sums) ----
  #pragma unroll
  for (int o = 32; o > 0; o >>= 1) {
    pen += __shfl_down(pen, o, 64);
    ct  += __shfl_down(ct,  o, 64);
    cp  += __shfl_down(cp,  o, 64);
  }
  const int wave = tid >> 6;
  if ((tid & 63) == 0) { sred[wave] = pen; sred[4 + wave] = ct; sred[8 + wave] = cp; }
  __syncthreads();
  if (tid == 0) {
    float P  = sred[0] + sred[1] + sred[2] + sred[3];
    float CT = (sred[4] + sred[5] + sred[6] + sred[7]) * (1.0f / 700.0f);
    float CP = (sred[8] + sred[9] + sred[10] + sred[11]) * (1.0f / 700.0f);
    float d = CT - CP;
    // loss = (sum penalties)/512 + mean_b (ct_b - cp_b)^2
    atomicAdd(out, (P + d * d) * (1.0f / 512.0f));
  }
}

extern "C" void kernel_launch(void* const* d_in, const int* in_sizes, int n_in,
                              void* d_out, int out_size, void* d_ws, size_t ws_size,
                              hipStream_t stream) {
  // harness re-poisons d_out to 0xAA before every timed launch -> zero it here
  hipMemsetAsync(d_out, 0, sizeof(float), stream);
  menu_loss_kernel<<<512, THREADS, 0, stream>>>(
      (const float4*)d_in[0], (const float4*)d_in[1],
      (const float*)d_in[2], (float*)d_out);
}

// Round 2
// 172.316 us; speedup vs baseline: 1.1508x; 1.1508x over previous
//
#include <hip/hip_runtime.h>
#include <cmath>

// MenuLoss, round 2: occupancy-driven restructure.
//   kernel A (1 block): build 223-entry pred-calorie table -> ws[0..222]
//   kernel B (2048 blocks = 512 batches x 4 slices): main compute; per-batch
//     ct/cp partials atomicAdd'd into ws, penalty into ws[256]
//   kernel C (1 block, 512 thr): finalize (ct-cp)^2 mean + penalties -> out
// ws layout (floats): [0..222] table | [256] pen accum | [512..1535] (ct,cp)x512

constexpr int NCOEF = 447;
constexpr int NTAB  = 223;
constexpr int PAIRS_PER_BATCH = 7168;   // 7*16*64
constexpr int SLICES = 4;               // blocks per batch
constexpr int TPB = 256;
constexpr int EPT = 7;                  // pairs per thread (1792 / 256)

__global__ __launch_bounds__(256)
void build_table(const float* __restrict__ coeffs, float* __restrict__ ws)
{
  int tid = threadIdx.x;
  if (tid >= NTAB) return;
  float k = (float)tid;
  float m = k / (1.0f + __expf(50.0f * (k - 222.5f)));  // == reference _mask at integers
  float xn = m / 111.0f - 1.0f;
  float x2 = xn + xn;
  float Tm = 1.0f, Tc = xn;
  float acc = fmaf(coeffs[1], xn, coeffs[0]);
  for (int i = 2; i < NCOEF; ++i) {
    float Tn = fmaf(x2, Tc, -Tm);
    acc = fmaf(coeffs[i], Tn, acc);
    Tm = Tc; Tc = Tn;
  }
  ws[tid] = acc;
}

__global__ __launch_bounds__(TPB)
void loss_main(const float2* __restrict__ yp, const float2* __restrict__ yt,
               const float* __restrict__ coeffs, float* __restrict__ ws)
{
  __shared__ float stab[NTAB];
  __shared__ float sred[12];

  const int tid = threadIdx.x;
  const int b = blockIdx.x >> 2;     // batch
  const int s = blockIdx.x & 3;      // slice

  if (tid < NTAB) stab[tid] = ws[tid];
  __syncthreads();

  const float2* P = yp + (size_t)b * PAIRS_PER_BATCH + s * (PAIRS_PER_BATCH / SLICES);
  const float2* T = yt + (size_t)b * PAIRS_PER_BATCH + s * (PAIRS_PER_BATCH / SLICES);

  float2 p[EPT], t[EPT];
  #pragma unroll
  for (int k = 0; k < EPT; ++k) { p[k] = P[tid + k * TPB]; t[k] = T[tid + k * TPB]; }

  float pen = 0.0f, cp = 0.0f;
  float x2[EPT], Tm[EPT], Tc[EPT], acc[EPT];

  #pragma unroll
  for (int k = 0; k < EPT; ++k) {
    float pid = p[k].x, pam = p[k].y;
    float izm = 1.0f - tanhf(4.0f * pid);
    float anm = tanhf(4.0f * pam);
    pen += izm * anm + (1.0f - izm) * (1.0f - anm) + fmaxf(pid - 222.0f, 0.0f);
    int idx = (int)rintf(pid);                       // half-even == jnp.round
    idx = idx < 0 ? 0 : (idx > NTAB - 1 ? NTAB - 1 : idx);
    cp = fmaf(stab[idx], pam, cp);
    float xn = t[k].x / 111.0f - 1.0f;               // exact div matches reference
    x2[k] = xn + xn; Tm[k] = 1.0f; Tc[k] = xn;
    acc[k] = fmaf(coeffs[1], xn, coeffs[0]);
  }

  // deg-446 recurrence, 7-wide ILP: 14 FMA per coeff per wave
  #pragma unroll 4
  for (int i = 2; i < NCOEF; ++i) {
    float c = coeffs[i];                             // uniform -> scalar load
    #pragma unroll
    for (int k = 0; k < EPT; ++k) {
      float Tn = fmaf(x2[k], Tc[k], -Tm[k]);
      acc[k] = fmaf(c, Tn, acc[k]);
      Tm[k] = Tc[k]; Tc[k] = Tn;
    }
  }

  float ct = 0.0f;
  #pragma unroll
  for (int k = 0; k < EPT; ++k) ct = fmaf(acc[k], t[k].y, ct);

  #pragma unroll
  for (int o = 32; o > 0; o >>= 1) {
    pen += __shfl_down(pen, o, 64);
    ct  += __shfl_down(ct,  o, 64);
    cp  += __shfl_down(cp,  o, 64);
  }
  const int w = tid >> 6;
  if ((tid & 63) == 0) { sred[w] = pen; sred[4 + w] = ct; sred[8 + w] = cp; }
  __syncthreads();
  if (tid == 0) {
    atomicAdd(ws + 256,            sred[0] + sred[1] + sred[2]  + sred[3]);
    atomicAdd(ws + 512 + 2 * b,    sred[4] + sred[5] + sred[6]  + sred[7]);
    atomicAdd(ws + 512 + 2 * b + 1, sred[8] + sred[9] + sred[10] + sred[11]);
  }
}

__global__ __launch_bounds__(512)
void finalize(const float* __restrict__ ws, float* __restrict__ out)
{
  __shared__ float sr[8];
  int t = threadIdx.x;
  float2 a = ((const float2*)(ws + 512))[t];
  float d = (a.x - a.y) * (1.0f / 700.0f);
  float v = d * d;
  #pragma unroll
  for (int o = 32; o > 0; o >>= 1) v += __shfl_down(v, o, 64);
  if ((t & 63) == 0) sr[t >> 6] = v;
  __syncthreads();
  if (t == 0) {
    float ssum = sr[0] + sr[1] + sr[2] + sr[3] + sr[4] + sr[5] + sr[6] + sr[7];
    out[0] = (ssum + ws[256]) * (1.0f / 512.0f);
  }
}

extern "C" void kernel_launch(void* const* d_in, const int* in_sizes, int n_in,
                              void* d_out, int out_size, void* d_ws, size_t ws_size,
                              hipStream_t stream) {
  const float2* yp = (const float2*)d_in[0];
  const float2* yt = (const float2*)d_in[1];
  const float* coeffs = (const float*)d_in[2];
  float* ws = (float*)d_ws;

  hipMemsetAsync(d_ws, 0, 1536 * sizeof(float), stream);   // accumulators start at 0
  build_table<<<1, 256, 0, stream>>>(coeffs, ws);
  loss_main<<<512 * SLICES, TPB, 0, stream>>>(yp, yt, coeffs, ws);
  finalize<<<1, 512, 0, stream>>>(ws, (float*)d_out);
}

// Round 3
// 169.175 us; speedup vs baseline: 1.1722x; 1.0186x over previous
//
#include <hip/hip_runtime.h>
#include <cmath>

// MenuLoss, round 3: zero-move pairwise Chebyshev recurrence.
// Two coeffs per step, in-place register update (no rotation moves):
//   Ta = fma(2x,Tb,-Ta)  -> T_i   ; acc += c_i   * Ta
//   Tb = fma(2x,Ta,-Tb)  -> T_i+1 ; acc += c_i+1 * Tb
// 4 FMA / 2 coeffs / point, register state identical at loop back-edge.
// ws layout (floats): [0..222] table | [256] pen accum | [512..1535] (ct,cp)x512

constexpr int NCOEF = 447;
constexpr int NTAB  = 223;
constexpr int PAIRS_PER_BATCH = 7168;   // 7*16*64
constexpr int SLICES = 4;               // 512*4 = 2048 blocks = 8/CU exactly
constexpr int TPB = 256;
constexpr int EPT = 7;                  // pairs per thread (1792 / 256)

__device__ __forceinline__ float tanh4(float v) {
  // v >= 0 here. tanh(4v) = 1 - 2/(exp(8v)+1); rcp approx is fine (penalty
  // tolerance is huge vs threshold). __expf(large) -> inf -> rcp -> 0 -> 1.
  float e = __expf(8.0f * v);
  return fmaf(-2.0f, __builtin_amdgcn_rcpf(e + 1.0f), 1.0f);
}

__global__ __launch_bounds__(256)
void build_table(const float* __restrict__ coeffs, float* __restrict__ ws)
{
  int tid = threadIdx.x;
  if (tid >= NTAB) return;
  float k = (float)tid;
  float m = k / (1.0f + __expf(50.0f * (k - 222.5f)));  // reference _mask at integers
  float xn = m / 111.0f - 1.0f;
  float x2 = xn + xn;
  float Ta = 1.0f, Tb = xn;
  float acc = fmaf(coeffs[1], xn, coeffs[0]);
  for (int i = 2; i + 1 < NCOEF; i += 2) {
    Ta = fmaf(x2, Tb, -Ta); acc = fmaf(coeffs[i],     Ta, acc);
    Tb = fmaf(x2, Ta, -Tb); acc = fmaf(coeffs[i + 1], Tb, acc);
  }
  Ta = fmaf(x2, Tb, -Ta); acc = fmaf(coeffs[NCOEF - 1], Ta, acc);  // i = 446
  ws[tid] = acc;
}

__global__ __launch_bounds__(TPB)
void loss_main(const float2* __restrict__ yp, const float2* __restrict__ yt,
               const float* __restrict__ coeffs, float* __restrict__ ws)
{
  __shared__ float stab[NTAB];
  __shared__ float sred[12];

  const int tid = threadIdx.x;
  const int b = blockIdx.x >> 2;     // batch
  const int s = blockIdx.x & 3;      // slice

  if (tid < NTAB) stab[tid] = ws[tid];
  __syncthreads();

  const float2* P = yp + (size_t)b * PAIRS_PER_BATCH + s * (PAIRS_PER_BATCH / SLICES);
  const float2* T = yt + (size_t)b * PAIRS_PER_BATCH + s * (PAIRS_PER_BATCH / SLICES);

  float pen = 0.0f, cp = 0.0f;
  float x2[EPT], Ta[EPT], Tb[EPT], acc[EPT], tam[EPT];

  // prologue: penalties + pred-table lookup + recurrence init; p-regs die here
  #pragma unroll
  for (int k = 0; k < EPT; ++k) {
    float2 pv = P[tid + k * TPB];
    float2 tv = T[tid + k * TPB];
    float a = tanh4(pv.x);                       // tanh(4*pred_id)
    float bb = tanh4(pv.y);                      // tanh(4*pred_amount)
    // (1-a)*b + a*(1-b) = a + b - 2ab
    pen += fmaf(bb, fmaf(-2.0f, a, 1.0f), a) + fmaxf(pv.x - 222.0f, 0.0f);
    int idx = (int)rintf(pv.x);                  // half-even == jnp.round
    idx = idx < 0 ? 0 : (idx > NTAB - 1 ? NTAB - 1 : idx);
    cp = fmaf(stab[idx], pv.y, cp);
    float xn = tv.x / 111.0f - 1.0f;             // exact div matches reference
    x2[k] = xn + xn; Ta[k] = 1.0f; Tb[k] = xn;
    acc[k] = fmaf(coeffs[1], xn, coeffs[0]);
    tam[k] = tv.y;
  }

  // deg-446 recurrence: 2 coeffs / 4 FMA per point per step, zero moves
  #pragma unroll 2
  for (int i = 2; i + 1 < NCOEF; i += 2) {
    float c0 = coeffs[i], c1 = coeffs[i + 1];    // uniform -> scalar loads
    #pragma unroll
    for (int k = 0; k < EPT; ++k) {
      Ta[k] = fmaf(x2[k], Tb[k], -Ta[k]); acc[k] = fmaf(c0, Ta[k], acc[k]);
      Tb[k] = fmaf(x2[k], Ta[k], -Tb[k]); acc[k] = fmaf(c1, Tb[k], acc[k]);
    }
  }
  {
    float c = coeffs[NCOEF - 1];                 // tail coeff i = 446
    #pragma unroll
    for (int k = 0; k < EPT; ++k) {
      Ta[k] = fmaf(x2[k], Tb[k], -Ta[k]); acc[k] = fmaf(c, Ta[k], acc[k]);
    }
  }

  float ct = 0.0f;
  #pragma unroll
  for (int k = 0; k < EPT; ++k) ct = fmaf(acc[k], tam[k], ct);

  #pragma unroll
  for (int o = 32; o > 0; o >>= 1) {
    pen += __shfl_down(pen, o, 64);
    ct  += __shfl_down(ct,  o, 64);
    cp  += __shfl_down(cp,  o, 64);
  }
  const int w = tid >> 6;
  if ((tid & 63) == 0) { sred[w] = pen; sred[4 + w] = ct; sred[8 + w] = cp; }
  __syncthreads();
  if (tid == 0) {
    atomicAdd(ws + 256,             sred[0] + sred[1] + sred[2]  + sred[3]);
    atomicAdd(ws + 512 + 2 * b,     sred[4] + sred[5] + sred[6]  + sred[7]);
    atomicAdd(ws + 512 + 2 * b + 1, sred[8] + sred[9] + sred[10] + sred[11]);
  }
}

__global__ __launch_bounds__(512)
void finalize(const float* __restrict__ ws, float* __restrict__ out)
{
  __shared__ float sr[8];
  int t = threadIdx.x;
  float2 a = ((const float2*)(ws + 512))[t];
  float d = (a.x - a.y) * (1.0f / 700.0f);
  float v = d * d;
  #pragma unroll
  for (int o = 32; o > 0; o >>= 1) v += __shfl_down(v, o, 64);
  if ((t & 63) == 0) sr[t >> 6] = v;
  __syncthreads();
  if (t == 0) {
    float ssum = sr[0] + sr[1] + sr[2] + sr[3] + sr[4] + sr[5] + sr[6] + sr[7];
    out[0] = (ssum + ws[256]) * (1.0f / 512.0f);
  }
}

extern "C" void kernel_launch(void* const* d_in, const int* in_sizes, int n_in,
                              void* d_out, int out_size, void* d_ws, size_t ws_size,
                              hipStream_t stream) {
  const float2* yp = (const float2*)d_in[0];
  const float2* yt = (const float2*)d_in[1];
  const float* coeffs = (const float*)d_in[2];
  float* ws = (float*)d_ws;

  hipMemsetAsync(d_ws, 0, 1536 * sizeof(float), stream);   // accumulators start at 0
  build_table<<<1, 256, 0, stream>>>(coeffs, ws);
  loss_main<<<512 * SLICES, TPB, 0, stream>>>(yp, yt, coeffs, ws);
  finalize<<<1, 512, 0, stream>>>(ws, (float*)d_out);
}

// Round 4
// 114.123 us; speedup vs baseline: 1.7377x; 1.4824x over previous
//
#include <hip/hip_runtime.h>
#include <cmath>

// MenuLoss, round 4: replace per-point deg-446 Chebyshev recurrence (890 FMA)
// with a 65537-node uniform-in-theta lookup table + linear interp (~25 VALU).
// g(theta) = sum_i c_i cos(i*theta) is band-limited in theta (max freq 446),
// so uniform-theta linear interp error ~ g''*h^2/8 ~ 5e-5/point; loss-scale
// error O(1) vs threshold 69.76 (loss ~ 3488). Pred side keeps the exact
// 223-entry integer table (ids round to 0..222) -> CP unchanged.
// Kernel becomes memory-bound: 57.6 MB inputs; table gathers hit per-XCD L2.

constexpr int NCOEF = 447;
constexpr int NTAB  = 223;
constexpr int M     = 65536;                 // interp intervals; M+1 nodes
constexpr float H_STEP = (float)(3.14159265358979323846 / 65536.0);
constexpr float SCALE  = (float)(65536.0 / 3.14159265358979323846);
constexpr int SLICES = 7;                    // blocks per batch (1024 pts each)
constexpr int TPB = 256;

__device__ float2 g_tab[M];                  // g_tab[i] = (f_i, f_{i+1}), 512 KB
__device__ float  g_pred[NTAB];              // exact table at integer ids
__device__ float4 g_part[512 * SLICES];      // per-block partials (pen, ct, cp, _)

__device__ __forceinline__ float tanh4(float v) {
  // v >= 0 here. tanh(4v) = 1 - 2/(exp(8v)+1); exp(large)->inf->rcp->0->1.
  float e = __expf(8.0f * v);
  return fmaf(-2.0f, __builtin_amdgcn_rcpf(e + 1.0f), 1.0f);
}

// One thread per table node (65537 theta nodes + 223 pred-integer nodes).
__global__ __launch_bounds__(256)
void build_tables(const float* __restrict__ coeffs)
{
  int g = blockIdx.x * 256 + threadIdx.x;
  float x;
  if (g <= M) {
    x = cosf((float)g * H_STEP);             // node value x_j = cos(j*h)
  } else if (g < M + 1 + NTAB) {
    float kf = (float)(g - (M + 1));
    float m = kf / (1.0f + __expf(50.0f * (kf - 222.5f)));  // reference _mask
    x = m / 111.0f - 1.0f;                   // exact div matches reference
  } else {
    return;
  }
  float x2 = x + x;
  float Ta = 1.0f, Tb = x;
  float acc = fmaf(coeffs[1], x, coeffs[0]);
  for (int i = 2; i + 1 < NCOEF; i += 2) {   // zero-move pairwise recurrence
    Ta = fmaf(x2, Tb, -Ta); acc = fmaf(coeffs[i],     Ta, acc);
    Tb = fmaf(x2, Ta, -Tb); acc = fmaf(coeffs[i + 1], Tb, acc);
  }
  Ta = fmaf(x2, Tb, -Ta); acc = fmaf(coeffs[NCOEF - 1], Ta, acc);  // i = 446

  if (g <= M) {                              // duplicate-store -> aligned float2 lookups
    if (g < M) g_tab[g].x = acc;
    if (g > 0) g_tab[g - 1].y = acc;
  } else {
    g_pred[g - (M + 1)] = acc;
  }
}

// grid (SLICES, 512): blockIdx.y = batch, blockIdx.x = slice of 1024 points.
__global__ __launch_bounds__(TPB)
void loss_main(const float2* __restrict__ yp, const float2* __restrict__ yt)
{
  __shared__ float spred[NTAB];
  __shared__ float sred[12];
  const int tid = threadIdx.x;

  if (tid < NTAB) spred[tid] = g_pred[tid];
  __syncthreads();

  const size_t base = (size_t)blockIdx.y * 7168 + (size_t)blockIdx.x * 1024;
  const float2* P = yp + base;
  const float2* T = yt + base;

  float pen = 0.0f, cp = 0.0f, ct = 0.0f;

  #pragma unroll
  for (int k = 0; k < 4; ++k) {
    float2 pv = P[tid + k * TPB];
    float2 tv = T[tid + k * TPB];

    // zeros/nonzeros + range penalties:  a + b - 2ab  (+ relu(id-222))
    float a = tanh4(pv.x);
    float bb = tanh4(pv.y);
    pen += fmaf(bb, fmaf(-2.0f, a, 1.0f), a) + fmaxf(pv.x - 222.0f, 0.0f);

    // pred calories: exact integer table (rintf = half-even = jnp.round)
    int idx = (int)rintf(pv.x);
    idx = idx < 0 ? 0 : (idx > NTAB - 1 ? NTAB - 1 : idx);
    cp = fmaf(spred[idx], pv.y, cp);

    // true calories: theta-space table + linear interp
    float xn = tv.x / 111.0f - 1.0f;         // exact div matches reference
    float t = acosf(xn) * SCALE;             // in [0, M]
    int i = (int)t;
    i = i > M - 1 ? M - 1 : i;
    float fr = t - (float)i;
    float2 f2 = g_tab[i];                    // one aligned 8B gather (L2-resident)
    float cal = fmaf(fr, f2.y - f2.x, f2.x);
    ct = fmaf(cal, tv.y, ct);
  }

  #pragma unroll
  for (int o = 32; o > 0; o >>= 1) {
    pen += __shfl_down(pen, o, 64);
    ct  += __shfl_down(ct,  o, 64);
    cp  += __shfl_down(cp,  o, 64);
  }
  const int w = tid >> 6;
  if ((tid & 63) == 0) { sred[w] = pen; sred[4 + w] = ct; sred[8 + w] = cp; }
  __syncthreads();
  if (tid == 0) {
    g_part[blockIdx.y * SLICES + blockIdx.x] =
        make_float4(sred[0] + sred[1] + sred[2]  + sred[3],
                    sred[4] + sred[5] + sred[6]  + sred[7],
                    sred[8] + sred[9] + sred[10] + sred[11], 0.0f);
  }
}

__global__ __launch_bounds__(512)
void finalize(float* __restrict__ out)
{
  __shared__ float sr[8];
  int t = threadIdx.x;                        // one thread per batch
  float pen = 0.0f, ct = 0.0f, cp = 0.0f;
  #pragma unroll
  for (int s = 0; s < SLICES; ++s) {
    float4 p = g_part[t * SLICES + s];
    pen += p.x; ct += p.y; cp += p.z;
  }
  float d = (ct - cp) * (1.0f / 700.0f);
  float v = fmaf(d, d, pen);                  // sum(v) = sum d^2 + sum pen
  #pragma unroll
  for (int o = 32; o > 0; o >>= 1) v += __shfl_down(v, o, 64);
  if ((t & 63) == 0) sr[t >> 6] = v;
  __syncthreads();
  if (t == 0) {
    out[0] = (sr[0] + sr[1] + sr[2] + sr[3] +
              sr[4] + sr[5] + sr[6] + sr[7]) * (1.0f / 512.0f);
  }
}

extern "C" void kernel_launch(void* const* d_in, const int* in_sizes, int n_in,
                              void* d_out, int out_size, void* d_ws, size_t ws_size,
                              hipStream_t stream) {
  build_tables<<<257, 256, 0, stream>>>((const float*)d_in[2]);
  loss_main<<<dim3(SLICES, 512), TPB, 0, stream>>>(
      (const float2*)d_in[0], (const float2*)d_in[1]);
  finalize<<<1, 512, 0, stream>>>((float*)d_out);
}